// Round 3
// baseline (1274.539 us; speedup 1.0000x reference)
//
#include <hip/hip_runtime.h>

#define H 192
#define W 192
#define HW (H*W)
#define G 32          // feature/ctx channels
#define C 64          // x channels
#define C2 128        // mean+var channels
#define C1 68         // conv1 out channels
#define B 6           // output batches
#define NB 2          // distinct ctx batches
#define OUTC 260      // 68 + 3*64
#define STRIP 48      // rows per mv block (old path)
#define SCH 8         // channels per sconv LDS chunk

// ---------------- shared front kernels ----------------

__global__ __launch_bounds__(256) void ctx_kernel(
    const float* __restrict__ feature, const float* __restrict__ w_ctx,
    const float* __restrict__ b_ctx, float* __restrict__ ctx)
{
    int p = blockIdx.x * 256 + threadIdx.x;
    int b = blockIdx.y;
    float f[G];
    const float* fp = feature + (size_t)b * G * HW + p;
#pragma unroll
    for (int k = 0; k < G; k++) f[k] = fp[k * HW];
    float* op = ctx + (size_t)b * G * HW + p;
    for (int o = 0; o < G; o++) {
        float acc = b_ctx[o];
#pragma unroll
        for (int k = 0; k < G; k++) acc += w_ctx[o * G + k] * f[k];
        op[o * HW] = acc;
    }
}

__global__ __launch_bounds__(256) void conv1_kernel(
    const float* __restrict__ ctx, const float* __restrict__ extra,
    const float* __restrict__ w1, const float* __restrict__ b1,
    float* __restrict__ out)
{
    int p = blockIdx.x * 256 + threadIdx.x;
    int b = blockIdx.y;
    float xv[C];
    const float* cp = ctx + (size_t)(b / 3) * G * HW + p;
#pragma unroll
    for (int k = 0; k < G; k++) xv[k] = cp[k * HW];
    const float* ep = extra + (size_t)b * G * HW + p;
#pragma unroll
    for (int k = 0; k < G; k++) xv[G + k] = ep[k * HW];
    float* op = out + (size_t)b * OUTC * HW + p;
    for (int o = 0; o < C1; o++) {
        float acc = b1[o];
#pragma unroll
        for (int k = 0; k < C; k++) acc += w1[o * C + k] * xv[k];
        op[o * HW] = acc;
    }
}

// ---------------- scan helpers ----------------

template<int CTRL, int RM>
__device__ __forceinline__ float dpp_mov0(float x) {
    return __int_as_float(__builtin_amdgcn_update_dpp(
        0, __float_as_int(x), CTRL, RM, 0xf, false));
}
// wave64 inclusive scan (LLVM AtomicOptimizer pattern)
__device__ __forceinline__ float wave_iscan(float x) {
    x += dpp_mov0<0x111, 0xf>(x);   // row_shr:1
    x += dpp_mov0<0x112, 0xf>(x);   // row_shr:2
    x += dpp_mov0<0x114, 0xf>(x);   // row_shr:4
    x += dpp_mov0<0x118, 0xf>(x);   // row_shr:8
    x += dpp_mov0<0x142, 0xa>(x);   // row_bcast:15 -> rows 1,3
    x += dpp_mov0<0x143, 0xc>(x);   // row_bcast:31 -> rows 2,3
    return x;
}

// weights for sconv, interleaved: wTi[si][c][0..63]=mean w, wTi[si][c][64..127]=var w
__global__ __launch_bounds__(256) void transpose_wi_kernel(
    const float* __restrict__ w0, const float* __restrict__ w1,
    const float* __restrict__ w2, float* __restrict__ wTi)
{
    int i = blockIdx.x * 256 + threadIdx.x;
    if (i >= 3 * C * C2) return;
    int si = i / (C * C2);
    int r = i % (C * C2);
    const float* ws = (si == 0) ? w0 : (si == 1) ? w1 : w2;
    int o = r / C2, ci = r % C2;
    int dst = (ci < C) ? (ci * (2 * C) + o) : ((ci - C) * (2 * C) + C + o);
    wTi[si * (C2 * C) + dst] = ws[r];
}

// K3'': barrier-free mv. One wave per (channel, 48-row strip, 48-col segment, batch).
// Wave covers 64 cols = 8 halo + 48 out + 8 halo (zero-padded at edges).
// Horizontal box: wave DPP prefix scan + 2 bpermute reads. No LDS, no barriers.
__global__ __launch_bounds__(64) void mv_all_kernel2(
    const float* __restrict__ ctx, const float* __restrict__ extra,
    int bbase, int nbs, float* __restrict__ mv)
{
    const int hk0 = 2, hk1 = 4, hk2 = 8;
    const int hks[3] = {hk0, hk1, hk2};

    int lane = threadIdx.x;                // 0..63
    int c = blockIdx.x;                    // channel
    int sy = blockIdx.y & 3;               // row strip
    int sx = blockIdx.y >> 2;              // col segment
    int bz = blockIdx.z;
    int b = bbase + bz;
    const float* src = (c < G) ? (ctx + ((size_t)(b / 3) * G + c) * HW)
                               : (extra + ((size_t)b * G + (c - G)) * HW);
    int col = sx * 48 - 8 + lane;          // -8..199
    bool colok = (col >= 0 && col < W);
    int h0 = sy * 48;

    // init vertical running windows at h0 (OOB rows/cols contribute 0)
    float s1[3] = {0.f, 0.f, 0.f}, s2[3] = {0.f, 0.f, 0.f};
#pragma unroll
    for (int dy = -hk2; dy <= hk2; ++dy) {
        int y = h0 + dy;
        float v = (colok && y >= 0 && y < H) ? src[y * W + col] : 0.f;
        float vv = v * v;
        if (dy >= -hk0 && dy <= hk0) { s1[0] += v; s2[0] += vv; }
        if (dy >= -hk1 && dy <= hk1) { s1[1] += v; s2[1] += vv; }
        s1[2] += v; s2[2] += vv;
    }

    bool outok = (lane >= 8 && lane < 56);
    float inv_nc[3];
#pragma unroll
    for (int k = 0; k < 3; ++k) {
        int x0 = max(col - hks[k], 0), x1 = min(col + hks[k], W - 1);
        inv_nc[k] = 1.0f / (float)(x1 - x0 + 1);
    }
    size_t sstride = (size_t)nbs * C * HW;
    float2* mvp = (float2*)mv + ((size_t)bz * C + c) * HW;

    for (int h = h0; h < h0 + 48; ++h) {
        if (h > h0) {
#pragma unroll
            for (int k = 0; k < 3; ++k) {
                int ya = h + hks[k], ys = h - hks[k] - 1;
                if (colok) {
                    if (ya < H)  { float v = src[ya * W + col]; s1[k] += v; s2[k] = fmaf(v, v, s2[k]); }
                    if (ys >= 0) { float v = src[ys * W + col]; s1[k] -= v; s2[k] = fmaf(-v, v, s2[k]); }
                }
            }
        }
#pragma unroll
        for (int k = 0; k < 3; ++k) {
            float p1 = wave_iscan(s1[k]);
            float p2 = wave_iscan(s2[k]);
            int ihi = lane + hks[k];        // <=63 for output lanes
            int ilo = lane - hks[k] - 1;    // >=-1 for output lanes
            float h1 = __shfl(p1, ihi & 63);
            float h2 = __shfl(p2, ihi & 63);
            float l1 = __shfl(p1, ilo & 63);
            float l2 = __shfl(p2, ilo & 63);
            if (ilo < 0) { l1 = 0.f; l2 = 0.f; }
            if (outok) {
                float t1 = h1 - l1;
                float t2 = h2 - l2;
                float inv_nr;
                if (h >= hks[k] && h + hks[k] < H) inv_nr = 1.0f / (float)(2 * hks[k] + 1);
                else inv_nr = 1.0f / (float)(min(h + hks[k], H - 1) - max(h - hks[k], 0) + 1);
                float ia = inv_nr * inv_nc[k];
                float mean = t1 * ia;
                float var = fmaf(t2, ia, -(mean * mean));
                mvp[(size_t)k * sstride + h * W + col] = make_float2(mean, var);
            }
        }
    }
}

// K4'': fused 1x1 conv 128->64 for all 3 scales. 512 threads = 256 px x 2 o-halves.
// mv staged in LDS chunks of SCH channels, double-buffered (issue-early/write-late).
__global__ __launch_bounds__(512) void sconv_all_kernel2(
    const float* __restrict__ mv, const float* __restrict__ wTi,
    const float* __restrict__ bs0, const float* __restrict__ bs1,
    const float* __restrict__ bs2,
    int bbase, int nbs, float* __restrict__ out)
{
    __shared__ float2 xs[2][SCH][256];
    int tid = threadIdx.x;
    int px = tid & 255;
    int oh = tid >> 8;                    // output half: 0 -> o 0..31, 1 -> o 32..63
    int p0 = blockIdx.x * 256;
    int bz = blockIdx.y;
    int si = blockIdx.z;
    size_t sstride = (size_t)nbs * C * HW;
    const float2* xp = (const float2*)mv + (size_t)si * sstride + (size_t)bz * C * HW + p0;
    const float* wp = wTi + si * (C2 * C);

    float2 r[4];
    // prologue: chunk 0 -> xs[0]
#pragma unroll
    for (int i = 0; i < 4; ++i) {
        int idx = i * 512 + tid;
        r[i] = xp[(size_t)(idx >> 8) * HW + (idx & 255)];
    }
#pragma unroll
    for (int i = 0; i < 4; ++i) {
        int idx = i * 512 + tid;
        xs[0][idx >> 8][idx & 255] = r[i];
    }
    __syncthreads();

    float acc[32];
#pragma unroll
    for (int o = 0; o < 32; ++o) acc[o] = 0.f;

    for (int cc = 0; cc < C / SCH; ++cc) {
        int cur = cc & 1;
        if (cc < C / SCH - 1) {
            // issue next chunk's global loads early; consumed after compute
#pragma unroll
            for (int i = 0; i < 4; ++i) {
                int idx = i * 512 + tid;
                r[i] = xp[(size_t)((cc + 1) * SCH + (idx >> 8)) * HW + (idx & 255)];
            }
        }
#pragma unroll
        for (int c = 0; c < SCH; ++c) {
            float2 v = xs[cur][c][px];
            const float* wrow = wp + (cc * SCH + c) * (2 * C) + oh * 32;
#pragma unroll
            for (int o = 0; o < 32; ++o)
                acc[o] = fmaf(wrow[o], v.x, fmaf(wrow[C + o], v.y, acc[o]));
        }
        if (cc < C / SCH - 1) {
#pragma unroll
            for (int i = 0; i < 4; ++i) {
                int idx = i * 512 + tid;
                xs[cur ^ 1][idx >> 8][idx & 255] = r[i];
            }
            __syncthreads();
        }
    }

    const float* bs = (si == 0) ? bs0 : (si == 1) ? bs1 : bs2;
    float* op = out + ((size_t)(bbase + bz) * OUTC + C1 + si * C + oh * 32) * HW + p0 + px;
#pragma unroll
    for (int o = 0; o < 32; ++o) op[(size_t)o * HW] = acc[o] + bs[oh * 32 + o];
}

// ---------------- OLD path kernels (fallback, verified) ----------------

__global__ __launch_bounds__(256) void transpose_w_kernel(
    const float* __restrict__ wsrc, float* __restrict__ wT, int oc, int ic)
{
    int i = blockIdx.x * 256 + threadIdx.x;
    if (i >= oc * ic) return;
    int o = i / ic, c = i % ic;
    wT[c * oc + o] = wsrc[i];
}

__global__ __launch_bounds__(192) void mv_kernel(
    const float* __restrict__ ctx, const float* __restrict__ extra,
    int half, int bbase, float* __restrict__ mv)
{
    __shared__ float ls1[2][W];
    __shared__ float ls2[2][W];
    int w = threadIdx.x;
    int c = blockIdx.x;
    int s = blockIdx.y;
    int bz = blockIdx.z;
    int b = bbase + bz;
    const float* src = (c < G)
        ? (ctx + ((size_t)(b / 3) * G + c) * HW)
        : (extra + ((size_t)b * G + (c - G)) * HW);

    int h0 = s * STRIP;
    int ya = max(h0 - half, 0);
    int yb = min(h0 + half, H - 1);
    float s1 = 0.f, s2 = 0.f;
    for (int y = ya; y <= yb; y++) { float v = src[y * W + w]; s1 += v; s2 += v * v; }

    int x0 = max(w - half, 0);
    int x1 = min(w + half, W - 1);
    float ncols = (float)(x1 - x0 + 1);

    size_t obase = ((size_t)bz * C2 + c) * HW;

    for (int h = h0; h < h0 + STRIP; h++) {
        if (h > h0) {
            int yadd = h + half;
            int ysub = h - half - 1;
            if (yadd <= H - 1) { float v = src[yadd * W + w]; s1 += v; s2 += v * v; }
            if (ysub >= 0)     { float v = src[ysub * W + w]; s1 -= v; s2 -= v * v; }
        }
        int buf = h & 1;
        ls1[buf][w] = s1;
        ls2[buf][w] = s2;
        __syncthreads();
        float t1 = 0.f, t2 = 0.f;
        for (int x = x0; x <= x1; x++) { t1 += ls1[buf][x]; t2 += ls2[buf][x]; }
        int nrows = min(h + half, H - 1) - max(h - half, 0) + 1;
        float inv_area = 1.0f / ((float)nrows * ncols);
        float mean = t1 * inv_area;
        float var  = t2 * inv_area - mean * mean;
        mv[obase + h * W + w] = mean;
        mv[obase + (size_t)C * HW + h * W + w] = var;
    }
}

__global__ __launch_bounds__(256) void sconv_kernel(
    const float* __restrict__ mv, const float* __restrict__ wT,
    const float* __restrict__ bsc, int bbase, int co, float* __restrict__ out)
{
    int p = blockIdx.x * 256 + threadIdx.x;
    int bz = blockIdx.y;
    int b = bbase + bz;
    const float* xp = mv + (size_t)bz * C2 * HW + p;
    float acc[C];
#pragma unroll
    for (int o = 0; o < C; o++) acc[o] = 0.f;
#pragma unroll 2
    for (int c = 0; c < C2; c++) {
        float v = xp[(size_t)c * HW];
        const float* wrow = wT + c * C;
#pragma unroll
        for (int o = 0; o < C; o++) acc[o] += wrow[o] * v;
    }
    float* op = out + ((size_t)b * OUTC + co) * HW + p;
#pragma unroll
    for (int o = 0; o < C; o++) op[o * HW] = acc[o] + bsc[o];
}

// ---------------- launch ----------------

extern "C" void kernel_launch(void* const* d_in, const int* in_sizes, int n_in,
                              void* d_out, int out_size, void* d_ws, size_t ws_size,
                              hipStream_t stream) {
    const float* feature = (const float*)d_in[0];
    const float* extra   = (const float*)d_in[1];
    const float* w_ctx   = (const float*)d_in[2];
    const float* b_ctx   = (const float*)d_in[3];
    const float* w1      = (const float*)d_in[4];
    const float* b1      = (const float*)d_in[5];
    const float* w_s[3]  = {(const float*)d_in[6], (const float*)d_in[8], (const float*)d_in[10]};
    const float* b_s[3]  = {(const float*)d_in[7], (const float*)d_in[9], (const float*)d_in[11]};
    float* out = (float*)d_out;

    // ws layout (floats)
    float* ctx = (float*)d_ws;                       // NB*G*HW
    float* wT  = ctx + (size_t)NB * G * HW;          // 3 * C2*C (planar or interleaved)
    float* mv  = wT + 3 * C2 * C;                    // new: B*3*C*HW*2 ; old: nb*C2*HW

    size_t base_bytes = ((size_t)NB * G * HW + 3 * C2 * C) * 4;
    size_t mv_new = (size_t)B * 3 * C * HW * 2 * 4;  // 6 slots x 3 scales, float2
    size_t mv_full = (size_t)B * C2 * HW * 4;        // old batched
    bool newpath = ws_size >= base_bytes + mv_new;

    ctx_kernel<<<dim3(HW / 256, NB), 256, 0, stream>>>(feature, w_ctx, b_ctx, ctx);
    conv1_kernel<<<dim3(HW / 256, B), 256, 0, stream>>>(ctx, extra, w1, b1, out);

    if (newpath) {
        transpose_wi_kernel<<<dim3((3 * C * C2 + 255) / 256), 256, 0, stream>>>(
            w_s[0], w_s[1], w_s[2], wT);
        mv_all_kernel2<<<dim3(C, 16, B), 64, 0, stream>>>(ctx, extra, 0, B, mv);
        sconv_all_kernel2<<<dim3(HW / 256, B, 3), 512, 0, stream>>>(
            mv, wT, b_s[0], b_s[1], b_s[2], 0, B, out);
    } else {
        for (int si = 0; si < 3; si++) {
            transpose_w_kernel<<<dim3((C2 * C + 255) / 256), 256, 0, stream>>>(
                w_s[si], wT + si * C2 * C, C, C2);
        }
        const int halves[3] = {2, 4, 8};
        bool batched = ws_size >= base_bytes + mv_full;
        if (batched) {
            for (int si = 0; si < 3; si++) {
                mv_kernel<<<dim3(C, H / STRIP, B), W, 0, stream>>>(ctx, extra, halves[si], 0, mv);
                sconv_kernel<<<dim3(HW / 256, B), 256, 0, stream>>>(
                    mv, wT + si * C2 * C, b_s[si], 0, C1 + si * C, out);
            }
        } else {
            for (int si = 0; si < 3; si++) {
                for (int b = 0; b < B; b++) {
                    mv_kernel<<<dim3(C, H / STRIP, 1), W, 0, stream>>>(ctx, extra, halves[si], b, mv);
                    sconv_kernel<<<dim3(HW / 256, 1), 256, 0, stream>>>(
                        mv, wT + si * C2 * C, b_s[si], b, C1 + si * C, out);
                }
            }
        }
    }
}

// Round 4
// 697.005 us; speedup vs baseline: 1.8286x; 1.8286x over previous
//
#include <hip/hip_runtime.h>

#define H 192
#define W 192
#define HW (H*W)
#define G 32          // feature/ctx channels
#define C 64          // x channels
#define C2 128        // mean+var channels
#define C1 68         // conv1 out channels
#define B 6           // output batches
#define NB 2          // distinct ctx batches
#define OUTC 260      // 68 + 3*64
#define STRIP 48      // rows per mv block (old path)

// ---------------- shared front kernels ----------------

__global__ __launch_bounds__(256) void ctx_kernel(
    const float* __restrict__ feature, const float* __restrict__ w_ctx,
    const float* __restrict__ b_ctx, float* __restrict__ ctx)
{
    int p = blockIdx.x * 256 + threadIdx.x;
    int b = blockIdx.y;
    float f[G];
    const float* fp = feature + (size_t)b * G * HW + p;
#pragma unroll
    for (int k = 0; k < G; k++) f[k] = fp[k * HW];
    float* op = ctx + (size_t)b * G * HW + p;
    for (int o = 0; o < G; o++) {
        float acc = b_ctx[o];
#pragma unroll
        for (int k = 0; k < G; k++) acc += w_ctx[o * G + k] * f[k];
        op[o * HW] = acc;
    }
}

__global__ __launch_bounds__(256) void conv1_kernel(
    const float* __restrict__ ctx, const float* __restrict__ extra,
    const float* __restrict__ w1, const float* __restrict__ b1,
    float* __restrict__ out)
{
    int p = blockIdx.x * 256 + threadIdx.x;
    int b = blockIdx.y;
    float xv[C];
    const float* cp = ctx + (size_t)(b / 3) * G * HW + p;
#pragma unroll
    for (int k = 0; k < G; k++) xv[k] = cp[k * HW];
    const float* ep = extra + (size_t)b * G * HW + p;
#pragma unroll
    for (int k = 0; k < G; k++) xv[G + k] = ep[k * HW];
    float* op = out + (size_t)b * OUTC * HW + p;
    for (int o = 0; o < C1; o++) {
        float acc = b1[o];
#pragma unroll
        for (int k = 0; k < C; k++) acc += w1[o * C + k] * xv[k];
        op[o * HW] = acc;
    }
}

// ---------------- scan helpers ----------------

template<int CTRL, int RM>
__device__ __forceinline__ float dpp_mov0(float x) {
    return __int_as_float(__builtin_amdgcn_update_dpp(
        0, __float_as_int(x), CTRL, RM, 0xf, false));
}
// wave64 inclusive scan (LLVM AtomicOptimizer pattern)
__device__ __forceinline__ float wave_iscan(float x) {
    x += dpp_mov0<0x111, 0xf>(x);   // row_shr:1
    x += dpp_mov0<0x112, 0xf>(x);   // row_shr:2
    x += dpp_mov0<0x114, 0xf>(x);   // row_shr:4
    x += dpp_mov0<0x118, 0xf>(x);   // row_shr:8
    x += dpp_mov0<0x142, 0xa>(x);   // row_bcast:15 -> rows 1,3
    x += dpp_mov0<0x143, 0xc>(x);   // row_bcast:31 -> rows 2,3
    return x;
}

// weights for sconv, interleaved: wTi[si][c][0..63]=mean w, wTi[si][c][64..127]=var w
__global__ __launch_bounds__(256) void transpose_wi_kernel(
    const float* __restrict__ w0, const float* __restrict__ w1,
    const float* __restrict__ w2, float* __restrict__ wTi)
{
    int i = blockIdx.x * 256 + threadIdx.x;
    if (i >= 3 * C * C2) return;
    int si = i / (C * C2);
    int r = i % (C * C2);
    const float* ws = (si == 0) ? w0 : (si == 1) ? w1 : w2;
    int o = r / C2, ci = r % C2;
    int dst = (ci < C) ? (ci * (2 * C) + o) : ((ci - C) * (2 * C) + C + o);
    wTi[si * (C2 * C) + dst] = ws[r];
}

// K3'': barrier-free mv. One wave per (channel, 48-row strip, 48-col segment, batch).
__global__ __launch_bounds__(64) void mv_all_kernel2(
    const float* __restrict__ ctx, const float* __restrict__ extra,
    int bbase, int nbs, float* __restrict__ mv)
{
    const int hk0 = 2, hk1 = 4, hk2 = 8;
    const int hks[3] = {hk0, hk1, hk2};

    int lane = threadIdx.x;                // 0..63
    int c = blockIdx.x;                    // channel
    int sy = blockIdx.y & 3;               // row strip
    int sx = blockIdx.y >> 2;              // col segment
    int bz = blockIdx.z;
    int b = bbase + bz;
    const float* src = (c < G) ? (ctx + ((size_t)(b / 3) * G + c) * HW)
                               : (extra + ((size_t)b * G + (c - G)) * HW);
    int col = sx * 48 - 8 + lane;          // -8..199
    bool colok = (col >= 0 && col < W);
    int h0 = sy * 48;

    float s1[3] = {0.f, 0.f, 0.f}, s2[3] = {0.f, 0.f, 0.f};
#pragma unroll
    for (int dy = -hk2; dy <= hk2; ++dy) {
        int y = h0 + dy;
        float v = (colok && y >= 0 && y < H) ? src[y * W + col] : 0.f;
        float vv = v * v;
        if (dy >= -hk0 && dy <= hk0) { s1[0] += v; s2[0] += vv; }
        if (dy >= -hk1 && dy <= hk1) { s1[1] += v; s2[1] += vv; }
        s1[2] += v; s2[2] += vv;
    }

    bool outok = (lane >= 8 && lane < 56);
    float inv_nc[3];
#pragma unroll
    for (int k = 0; k < 3; ++k) {
        int x0 = max(col - hks[k], 0), x1 = min(col + hks[k], W - 1);
        inv_nc[k] = 1.0f / (float)(x1 - x0 + 1);
    }
    size_t sstride = (size_t)nbs * C * HW;
    float2* mvp = (float2*)mv + ((size_t)bz * C + c) * HW;

    for (int h = h0; h < h0 + 48; ++h) {
        if (h > h0) {
#pragma unroll
            for (int k = 0; k < 3; ++k) {
                int ya = h + hks[k], ys = h - hks[k] - 1;
                if (colok) {
                    if (ya < H)  { float v = src[ya * W + col]; s1[k] += v; s2[k] = fmaf(v, v, s2[k]); }
                    if (ys >= 0) { float v = src[ys * W + col]; s1[k] -= v; s2[k] = fmaf(-v, v, s2[k]); }
                }
            }
        }
#pragma unroll
        for (int k = 0; k < 3; ++k) {
            float p1 = wave_iscan(s1[k]);
            float p2 = wave_iscan(s2[k]);
            int ihi = lane + hks[k];        // <=63 for output lanes
            int ilo = lane - hks[k] - 1;    // >=-1 for output lanes
            float h1 = __shfl(p1, ihi & 63);
            float h2 = __shfl(p2, ihi & 63);
            float l1 = __shfl(p1, ilo & 63);
            float l2 = __shfl(p2, ilo & 63);
            if (ilo < 0) { l1 = 0.f; l2 = 0.f; }
            if (outok) {
                float t1 = h1 - l1;
                float t2 = h2 - l2;
                float inv_nr;
                if (h >= hks[k] && h + hks[k] < H) inv_nr = 1.0f / (float)(2 * hks[k] + 1);
                else inv_nr = 1.0f / (float)(min(h + hks[k], H - 1) - max(h - hks[k], 0) + 1);
                float ia = inv_nr * inv_nc[k];
                float mean = t1 * ia;
                float var = fmaf(t2, ia, -(mean * mean));
                mvp[(size_t)k * sstride + h * W + col] = make_float2(mean, var);
            }
        }
    }
}

// K4''': 1x1 conv 128->64. 256 threads; each thread = 4 pixels x 16 outputs.
// Weights for this block's (scale, o-group) staged in LDS once (2KB, uniform
// broadcast reads). mv read directly from global, coalesced float4. No
// main-loop barriers, no global weight loads.
// grid: (HW/1024, B, 12) with z = si*4 + og.
__global__ __launch_bounds__(256) void sconv_all_kernel3(
    const float* __restrict__ mv, const float* __restrict__ wTi,
    const float* __restrict__ bs0, const float* __restrict__ bs1,
    const float* __restrict__ bs2,
    int bbase, int nbs, float* __restrict__ out)
{
    __shared__ float ls_w[C * 32];         // [c][0..15]=mean w, [16..31]=var w
    int t = threadIdx.x;
    int si = blockIdx.z >> 2;
    int og = blockIdx.z & 3;
    int bz = blockIdx.y;
    int p0 = blockIdx.x * 1024;

    // stage weights: 2048 floats
    const float* wp = wTi + si * (C2 * C);
#pragma unroll
    for (int i = t; i < C * 32; i += 256) {
        int c = i >> 5, j = i & 31;
        int col = (j < 16) ? (og * 16 + j) : (64 + og * 16 + (j - 16));
        ls_w[i] = wp[c * (2 * C) + col];
    }
    __syncthreads();

    size_t sstride = (size_t)nbs * C * HW;
    const float2* xbase = (const float2*)mv + (size_t)si * sstride
                        + (size_t)bz * C * HW + p0 + 4 * t;

    float acc[4][16];
#pragma unroll
    for (int px = 0; px < 4; ++px)
#pragma unroll
        for (int o = 0; o < 16; ++o) acc[px][o] = 0.f;

#pragma unroll 2
    for (int c = 0; c < C; ++c) {
        const float4* q = (const float4*)(xbase + (size_t)c * HW);
        float4 xA = q[0];                  // m0 v0 m1 v1
        float4 xB = q[1];                  // m2 v2 m3 v3
        const float4* wq = (const float4*)(ls_w + c * 32);
        float wm[16], wv[16];
        *(float4*)&wm[0]  = wq[0]; *(float4*)&wm[4]  = wq[1];
        *(float4*)&wm[8]  = wq[2]; *(float4*)&wm[12] = wq[3];
        *(float4*)&wv[0]  = wq[4]; *(float4*)&wv[4]  = wq[5];
        *(float4*)&wv[8]  = wq[6]; *(float4*)&wv[12] = wq[7];
        float m[4] = {xA.x, xA.z, xB.x, xB.z};
        float v[4] = {xA.y, xA.w, xB.y, xB.w};
#pragma unroll
        for (int px = 0; px < 4; ++px)
#pragma unroll
            for (int o = 0; o < 16; ++o)
                acc[px][o] = fmaf(wm[o], m[px], fmaf(wv[o], v[px], acc[px][o]));
    }

    const float* bs = (si == 0) ? bs0 : (si == 1) ? bs1 : bs2;
    float* op = out + ((size_t)(bbase + bz) * OUTC + C1 + si * C + og * 16) * HW
              + p0 + 4 * t;
#pragma unroll
    for (int o = 0; o < 16; ++o) {
        float bb = bs[og * 16 + o];
        float4 st = make_float4(acc[0][o] + bb, acc[1][o] + bb,
                                acc[2][o] + bb, acc[3][o] + bb);
        *(float4*)(op + (size_t)o * HW) = st;
    }
}

// ---------------- OLD path kernels (fallback, verified) ----------------

__global__ __launch_bounds__(256) void transpose_w_kernel(
    const float* __restrict__ wsrc, float* __restrict__ wT, int oc, int ic)
{
    int i = blockIdx.x * 256 + threadIdx.x;
    if (i >= oc * ic) return;
    int o = i / ic, c = i % ic;
    wT[c * oc + o] = wsrc[i];
}

__global__ __launch_bounds__(192) void mv_kernel(
    const float* __restrict__ ctx, const float* __restrict__ extra,
    int half, int bbase, float* __restrict__ mv)
{
    __shared__ float ls1[2][W];
    __shared__ float ls2[2][W];
    int w = threadIdx.x;
    int c = blockIdx.x;
    int s = blockIdx.y;
    int bz = blockIdx.z;
    int b = bbase + bz;
    const float* src = (c < G)
        ? (ctx + ((size_t)(b / 3) * G + c) * HW)
        : (extra + ((size_t)b * G + (c - G)) * HW);

    int h0 = s * STRIP;
    int ya = max(h0 - half, 0);
    int yb = min(h0 + half, H - 1);
    float s1 = 0.f, s2 = 0.f;
    for (int y = ya; y <= yb; y++) { float v = src[y * W + w]; s1 += v; s2 += v * v; }

    int x0 = max(w - half, 0);
    int x1 = min(w + half, W - 1);
    float ncols = (float)(x1 - x0 + 1);

    size_t obase = ((size_t)bz * C2 + c) * HW;

    for (int h = h0; h < h0 + STRIP; h++) {
        if (h > h0) {
            int yadd = h + half;
            int ysub = h - half - 1;
            if (yadd <= H - 1) { float v = src[yadd * W + w]; s1 += v; s2 += v * v; }
            if (ysub >= 0)     { float v = src[ysub * W + w]; s1 -= v; s2 -= v * v; }
        }
        int buf = h & 1;
        ls1[buf][w] = s1;
        ls2[buf][w] = s2;
        __syncthreads();
        float t1 = 0.f, t2 = 0.f;
        for (int x = x0; x <= x1; x++) { t1 += ls1[buf][x]; t2 += ls2[buf][x]; }
        int nrows = min(h + half, H - 1) - max(h - half, 0) + 1;
        float inv_area = 1.0f / ((float)nrows * ncols);
        float mean = t1 * inv_area;
        float var  = t2 * inv_area - mean * mean;
        mv[obase + h * W + w] = mean;
        mv[obase + (size_t)C * HW + h * W + w] = var;
    }
}

__global__ __launch_bounds__(256) void sconv_kernel(
    const float* __restrict__ mv, const float* __restrict__ wT,
    const float* __restrict__ bsc, int bbase, int co, float* __restrict__ out)
{
    int p = blockIdx.x * 256 + threadIdx.x;
    int bz = blockIdx.y;
    int b = bbase + bz;
    const float* xp = mv + (size_t)bz * C2 * HW + p;
    float acc[C];
#pragma unroll
    for (int o = 0; o < C; o++) acc[o] = 0.f;
#pragma unroll 2
    for (int c = 0; c < C2; c++) {
        float v = xp[(size_t)c * HW];
        const float* wrow = wT + c * C;
#pragma unroll
        for (int o = 0; o < C; o++) acc[o] += wrow[o] * v;
    }
    float* op = out + ((size_t)b * OUTC + co) * HW + p;
#pragma unroll
    for (int o = 0; o < C; o++) op[o * HW] = acc[o] + bsc[o];
}

// ---------------- launch ----------------

extern "C" void kernel_launch(void* const* d_in, const int* in_sizes, int n_in,
                              void* d_out, int out_size, void* d_ws, size_t ws_size,
                              hipStream_t stream) {
    const float* feature = (const float*)d_in[0];
    const float* extra   = (const float*)d_in[1];
    const float* w_ctx   = (const float*)d_in[2];
    const float* b_ctx   = (const float*)d_in[3];
    const float* w1      = (const float*)d_in[4];
    const float* b1      = (const float*)d_in[5];
    const float* w_s[3]  = {(const float*)d_in[6], (const float*)d_in[8], (const float*)d_in[10]};
    const float* b_s[3]  = {(const float*)d_in[7], (const float*)d_in[9], (const float*)d_in[11]};
    float* out = (float*)d_out;

    // ws layout (floats)
    float* ctx = (float*)d_ws;                       // NB*G*HW
    float* wT  = ctx + (size_t)NB * G * HW;          // 3 * C2*C (planar or interleaved)
    float* mv  = wT + 3 * C2 * C;                    // new: B*3*C*HW*2 ; old: nb*C2*HW

    size_t base_bytes = ((size_t)NB * G * HW + 3 * C2 * C) * 4;
    size_t mv_new = (size_t)B * 3 * C * HW * 2 * 4;  // 6 slots x 3 scales, float2
    size_t mv_full = (size_t)B * C2 * HW * 4;        // old batched
    bool newpath = ws_size >= base_bytes + mv_new;

    ctx_kernel<<<dim3(HW / 256, NB), 256, 0, stream>>>(feature, w_ctx, b_ctx, ctx);
    conv1_kernel<<<dim3(HW / 256, B), 256, 0, stream>>>(ctx, extra, w1, b1, out);

    if (newpath) {
        transpose_wi_kernel<<<dim3((3 * C * C2 + 255) / 256), 256, 0, stream>>>(
            w_s[0], w_s[1], w_s[2], wT);
        mv_all_kernel2<<<dim3(C, 16, B), 64, 0, stream>>>(ctx, extra, 0, B, mv);
        sconv_all_kernel3<<<dim3(HW / 1024, B, 12), 256, 0, stream>>>(
            mv, wT, b_s[0], b_s[1], b_s[2], 0, B, out);
    } else {
        for (int si = 0; si < 3; si++) {
            transpose_w_kernel<<<dim3((C2 * C + 255) / 256), 256, 0, stream>>>(
                w_s[si], wT + si * C2 * C, C, C2);
        }
        const int halves[3] = {2, 4, 8};
        bool batched = ws_size >= base_bytes + mv_full;
        if (batched) {
            for (int si = 0; si < 3; si++) {
                mv_kernel<<<dim3(C, H / STRIP, B), W, 0, stream>>>(ctx, extra, halves[si], 0, mv);
                sconv_kernel<<<dim3(HW / 256, B), 256, 0, stream>>>(
                    mv, wT + si * C2 * C, b_s[si], 0, C1 + si * C, out);
            }
        } else {
            for (int si = 0; si < 3; si++) {
                for (int b = 0; b < B; b++) {
                    mv_kernel<<<dim3(C, H / STRIP, 1), W, 0, stream>>>(ctx, extra, halves[si], b, mv);
                    sconv_kernel<<<dim3(HW / 256, 1), 256, 0, stream>>>(
                        mv, wT + si * C2 * C, b_s[si], b, C1 + si * C, out);
                }
            }
        }
    }
}